// Round 4
// baseline (127.939 us; speedup 1.0000x reference)
//
#include <hip/hip_runtime.h>
#include <cstdint>

typedef unsigned long long u64;
typedef unsigned short u16;

#define H_IMG 2048
#define W_IMG 2048
#define WPR   32                  // u64 words per image row
#define F4PR  512                 // float4 per image row
#define NPIX  (H_IMG * W_IMG)

#define TILE_H    8               // image rows produced per block
#define MAX_STEPS 16              // == twice-validated global iterate count
#define HALO      (2 * MAX_STEPS) // 32 halo rows each side (2 rows/step)
#define PH        (TILE_H + 2 * HALO)  // 72 padded rows
#define RS        33              // LDS row stride (u64), +1 to decorrelate banks
#define RPG       (PH / 8)        // 9 padded rows per thread-row-group

// ---------------- single fused kernel: thresholds + bitmaps + flood + outputs ----------------
// Block b owns image rows [8b, 8b+8). It reads thin for its 72-row padded window
// (halo re-reads hit LLC: whole image is 16 MB), builds weak/strong bitmaps
// directly in LDS (u16 chunks; little-endian => u64 bitmap), writes out_low/out_high
// for owned rows, runs up to 16 dilation steps with block-local early exit
// (monotone dilation: unchanged window == local fixed point => interior equals
// the global 16-step iterate, bit-exact vs R2/R3 validated), then writes out_final.
__global__ __launch_bounds__(256) void hyst_fused(const float4* __restrict__ thin4,
                                                  float4* __restrict__ lo4,
                                                  float4* __restrict__ hi4,
                                                  float4* __restrict__ out4) {
    __shared__ u64 bufA[PH * RS];   // strong/active bitmap (phase 1 writes as u16)
    __shared__ u64 bufB[PH * RS];
    __shared__ u64 wkL [PH * RS];   // weak bitmap
    __shared__ int chg;

    const int tid = threadIdx.x;
    const int rowBase = (int)blockIdx.x * TILE_H - HALO;  // image row of padded row 0

    // ---- phase 1: build bitmaps in LDS; store lo/hi for owned rows ----
    u16* stL16 = (u16*)bufA;
    u16* wkL16 = (u16*)wkL;
    for (int i = tid; i < PH * 128; i += 256) {     // 36 iters; 128 u16-chunks/row
        int lr  = i >> 7;                           // padded row
        int pos = i & 127;                          // 16-px chunk within row
        int gy  = rowBase + lr;
        unsigned wm = 0, sm = 0;
        if ((unsigned)gy < (unsigned)H_IMG) {
            int f0 = gy * F4PR + pos * 4;
            bool owned = (lr >= HALO) && (lr < HALO + TILE_H);
            #pragma unroll
            for (int j = 0; j < 4; ++j) {
                float4 v = thin4[f0 + j];
                float4 lo, hi;
                lo.x = (v.x < 0.3f) ? 0.0f : v.x;  hi.x = (v.x < 0.7f) ? 0.0f : v.x;
                lo.y = (v.y < 0.3f) ? 0.0f : v.y;  hi.y = (v.y < 0.7f) ? 0.0f : v.y;
                lo.z = (v.z < 0.3f) ? 0.0f : v.z;  hi.z = (v.z < 0.7f) ? 0.0f : v.z;
                lo.w = (v.w < 0.3f) ? 0.0f : v.w;  hi.w = (v.w < 0.7f) ? 0.0f : v.w;
                if (owned) { lo4[f0 + j] = lo; hi4[f0 + j] = hi; }
                wm |= ((v.x >= 0.3f) ? 1u : 0u) << (4 * j + 0);
                wm |= ((v.y >= 0.3f) ? 1u : 0u) << (4 * j + 1);
                wm |= ((v.z >= 0.3f) ? 1u : 0u) << (4 * j + 2);
                wm |= ((v.w >= 0.3f) ? 1u : 0u) << (4 * j + 3);
                sm |= ((v.x >= 0.7f) ? 1u : 0u) << (4 * j + 0);
                sm |= ((v.y >= 0.7f) ? 1u : 0u) << (4 * j + 1);
                sm |= ((v.z >= 0.7f) ? 1u : 0u) << (4 * j + 2);
                sm |= ((v.w >= 0.7f) ? 1u : 0u) << (4 * j + 3);
            }
        }
        // u16 index (lr*RS + pos>>2)*4 + (pos&3) == lr*RS*4 + pos
        stL16[lr * RS * 4 + pos] = (u16)sm;
        wkL16[lr * RS * 4 + pos] = (u16)wm;
    }
    __syncthreads();

    // ---- phase 2: flood fill on LDS bitmaps ----
    const int c  = tid & 31;           // word column
    const int tg = tid >> 5;           // thread-row group 0..7
    const int r0 = tg * RPG;           // first owned padded row

    // per-owned-row invariants in registers (weak word + boundary masks)
    u64 wreg[RPG], m1r[RPG], m2r[RPG];
    #pragma unroll
    for (int k = 0; k < RPG; ++k) {
        int lr = r0 + k;
        int gy = rowBase + lr;
        wreg[k] = wkL[lr * RS + c];
        u64 m1 = (gy >= 1 && gy + 1 < H_IMG - 1) ? ~0ull : 0ull;
        u64 m2 = (gy >= 2 && gy + 2 < H_IMG - 1) ? ~0ull : 0ull;
        if (c == 0)       { m1 &= ~1ull;         m2 &= ~3ull; }
        if (c == WPR - 1) { m1 &= ~(3ull << 62); m2 &= ~(7ull << 61); }
        m1r[k] = m1;
        m2r[k] = m2;
    }

    u64* cur = bufA;
    u64* nxt = bufB;

    for (int it = 0; it < MAX_STEPS; ++it) {
        if (tid == 0) chg = 0;
        __syncthreads();                       // reset visible; prev writes visible

        u64 cc[5], s1[5], s2[5];
        int myc = 0;

        #define LOAD_ROW(slot, LR) do {                                          \
            int _lr = (LR);                                                      \
            u64 _C = 0, _L = 0, _R = 0;                                          \
            if ((unsigned)_lr < (unsigned)PH) {                                  \
                _C = cur[_lr * RS + c];                                          \
                if (c > 0)       _L = cur[_lr * RS + c - 1];                     \
                if (c < WPR - 1) _R = cur[_lr * RS + c + 1];                     \
            }                                                                    \
            cc[slot] = _C;                                                       \
            s1[slot] = ((_C << 1) | (_L >> 63)) | ((_C >> 1) | (_R << 63));      \
            s2[slot] = ((_C << 2) | (_L >> 62)) | ((_C >> 2) | (_R << 62));      \
        } while (0)

        LOAD_ROW(0, r0 - 2);
        LOAD_ROW(1, r0 - 1);
        LOAD_ROW(2, r0);
        LOAD_ROW(3, r0 + 1);

        #pragma unroll
        for (int k = 0; k < RPG; ++k) {
            LOAD_ROW(4, r0 + k + 2);
            u64 a1 = (s1[1] | cc[1]) | (s1[3] | cc[3]) | s1[2];
            u64 a2 = (s2[0] | cc[0]) | (s2[4] | cc[4]) | s2[2];
            u64 nv = cc[2] | (wreg[k] & ((m1r[k] & a1) | (m2r[k] & a2)));
            nxt[(r0 + k) * RS + c] = nv;
            myc |= (nv != cc[2]);
            cc[0] = cc[1]; cc[1] = cc[2]; cc[2] = cc[3]; cc[3] = cc[4];
            s1[0] = s1[1]; s1[1] = s1[2]; s1[2] = s1[3]; s1[3] = s1[4];
            s2[0] = s2[1]; s2[1] = s2[2]; s2[2] = s2[3]; s2[3] = s2[4];
        }
        #undef LOAD_ROW

        if (myc) chg = 1;                      // race-benign (all write 1)
        __syncthreads();                       // writes + chg sets done
        int done = (chg == 0);
        __syncthreads();                       // chg reads done before next reset
        u64* t = cur; cur = nxt; nxt = t;
        if (done) break;
    }

    // ---- phase 3: out_final for owned rows (float4 stores) ----
    // hi>0 => active seed, final=hi=lo(v); promoted weak => lo(v); else 0.
    const int B = blockIdx.x;
    #pragma unroll
    for (int j = 0; j < 16; ++j) {
        int f   = tid + 256 * j;               // float4 idx within tile, 0..4095
        int px  = f * 4;
        int r   = px >> 11;                    // local image row 0..7
        int col = px & 2047;
        u64 w   = cur[(HALO + r) * RS + (col >> 6)];
        int b   = col & 63;
        float4 v = thin4[B * 4096 + f];        // L1/L2-hot (read in phase 1)
        float4 o;
        o.x = ((w >> (b + 0)) & 1ull) ? ((v.x < 0.3f) ? 0.0f : v.x) : 0.0f;
        o.y = ((w >> (b + 1)) & 1ull) ? ((v.y < 0.3f) ? 0.0f : v.y) : 0.0f;
        o.z = ((w >> (b + 2)) & 1ull) ? ((v.z < 0.3f) ? 0.0f : v.z) : 0.0f;
        o.w = ((w >> (b + 3)) & 1ull) ? ((v.w < 0.3f) ? 0.0f : v.w) : 0.0f;
        out4[B * 4096 + f] = o;
    }
}

extern "C" void kernel_launch(void* const* d_in, const int* in_sizes, int n_in,
                              void* d_out, int out_size, void* d_ws, size_t ws_size,
                              hipStream_t stream) {
    const float* thin = (const float*)d_in[0];   // grad_magnitude/orientation unused
    float* out_low   = (float*)d_out;
    float* out_high  = out_low + NPIX;
    float* out_final = out_high + NPIX;
    (void)d_ws; (void)ws_size;                   // no workspace needed

    hyst_fused<<<H_IMG / TILE_H, 256, 0, stream>>>(
        (const float4*)thin, (float4*)out_low, (float4*)out_high, (float4*)out_final);
}